// Round 1
// baseline (2566.682 us; speedup 1.0000x reference)
//
#include <hip/hip_runtime.h>
#include <cstdint>
#include <cstddef>

#define B_    4
#define L_    1024
#define ENCIN 64
#define DM    512
#define H_    8
#define HD    64
#define DFF   2048
#define NL    3
#define COUT  64
#define SCALE 0.125f

// ---------------------------------------------------------------------------
// Generic fp32 GEMM: C[M,N] = A[M,K] @ W[K,N] + bias, BM=128 BN=64 BK=16,
// 256 threads, 8x4 per thread. Requires M%128==0, N%64==0, K%16==0.
// MODE: 0 plain, 1 write in [B,H,L,HD] layout (QKV), 2 gelu epilogue,
//       3 add positional encoding (embedding).
// ---------------------------------------------------------------------------
template<int MODE>
__global__ __launch_bounds__(256) void gemm_k(const float* __restrict__ A,
    const float* __restrict__ W, const float* __restrict__ bias,
    float* __restrict__ C, int M, int N, int K)
{
  __shared__ float As[16][132];
  __shared__ float Bs[16][68];
  const int t  = threadIdx.x;
  const int tx = t & 15, ty = t >> 4;
  const int m0 = blockIdx.y * 128, n0 = blockIdx.x * 64;

  float acc[8][4];
#pragma unroll
  for (int i = 0; i < 8; i++)
#pragma unroll
    for (int j = 0; j < 4; j++) acc[i][j] = 0.f;

  for (int kt = 0; kt < K; kt += 16) {
#pragma unroll
    for (int i = 0; i < 2; i++) {              // A tile 128x16
      int f = t + 256 * i;
      int row = f >> 2, kq = f & 3;
      const float4 v = *(const float4*)&A[(size_t)(m0 + row) * K + kt + kq * 4];
      As[kq * 4 + 0][row] = v.x; As[kq * 4 + 1][row] = v.y;
      As[kq * 4 + 2][row] = v.z; As[kq * 4 + 3][row] = v.w;
    }
    {                                          // B tile 16x64
      int brow = t >> 4, c4 = t & 15;
      const float4 v = *(const float4*)&W[(size_t)(kt + brow) * N + n0 + c4 * 4];
      *(float4*)&Bs[brow][c4 * 4] = v;
    }
    __syncthreads();
#pragma unroll
    for (int kk = 0; kk < 16; kk++) {
      float4 a0 = *(const float4*)&As[kk][ty * 8];
      float4 a1 = *(const float4*)&As[kk][ty * 8 + 4];
      float4 b4 = *(const float4*)&Bs[kk][tx * 4];
      float a[8] = {a0.x, a0.y, a0.z, a0.w, a1.x, a1.y, a1.z, a1.w};
      float bb[4] = {b4.x, b4.y, b4.z, b4.w};
#pragma unroll
      for (int i = 0; i < 8; i++)
#pragma unroll
        for (int j = 0; j < 4; j++) acc[i][j] += a[i] * bb[j];
    }
    __syncthreads();
  }

  const int col = n0 + tx * 4;
  const float4 bv = *(const float4*)&bias[col];
#pragma unroll
  for (int i = 0; i < 8; i++) {
    int row = m0 + ty * 8 + i;
    float o[4] = {acc[i][0] + bv.x, acc[i][1] + bv.y,
                  acc[i][2] + bv.z, acc[i][3] + bv.w};
    if (MODE == 2) {
#pragma unroll
      for (int j = 0; j < 4; j++)
        o[j] = 0.5f * o[j] * (1.0f + erff(o[j] * 0.70710678118654752f));
    }
    if (MODE == 3) {
      int l = row & (L_ - 1);
#pragma unroll
      for (int j = 0; j < 4; j++) {
        int n = col + j;
        float dv = expf((float)(n & ~1) * -0.017988946039015984f);
        float ang = (float)l * dv;
        o[j] += (n & 1) ? cosf(ang) : sinf(ang);
      }
    }
    float4 ov = make_float4(o[0], o[1], o[2], o[3]);
    if (MODE == 1) {
      int bb_ = row >> 10, l = row & (L_ - 1), h = col >> 6, hd = col & 63;
      *(float4*)&C[(((size_t)(bb_ * H_ + h)) * L_ + l) * HD + hd] = ov;
    } else {
      *(float4*)&C[(size_t)row * N + col] = ov;
    }
  }
}

// ---------------------------------------------------------------------------
// qk: S[bh, m, n] = q[bh,m,:] . k[bh,n,:]   (unscaled)
// BM=128 BN=64, K=64 in two 32-steps, 256 threads, 8x4 per thread
// ---------------------------------------------------------------------------
__global__ __launch_bounds__(256) void qk_k(const float* __restrict__ q,
    const float* __restrict__ k, float* __restrict__ S)
{
  __shared__ float Qs[32][132];
  __shared__ float Ks[32][68];
  const int t = threadIdx.x, tx = t & 15, ty = t >> 4;
  const int n0 = blockIdx.x * 64, m0 = blockIdx.y * 128, bh = blockIdx.z;
  const float* qb = q + (size_t)bh * L_ * HD;
  const float* kb = k + (size_t)bh * L_ * HD;

  float acc[8][4];
#pragma unroll
  for (int i = 0; i < 8; i++)
#pragma unroll
    for (int j = 0; j < 4; j++) acc[i][j] = 0.f;

  for (int kt = 0; kt < HD; kt += 32) {
#pragma unroll
    for (int i = 0; i < 4; i++) {              // Q tile 128x32 (transposed)
      int f = t + 256 * i;
      int row = f >> 3, c4 = f & 7;
      float4 v = *(const float4*)&qb[(size_t)(m0 + row) * HD + kt + c4 * 4];
      Qs[c4 * 4 + 0][row] = v.x; Qs[c4 * 4 + 1][row] = v.y;
      Qs[c4 * 4 + 2][row] = v.z; Qs[c4 * 4 + 3][row] = v.w;
    }
#pragma unroll
    for (int i = 0; i < 2; i++) {              // K tile 64x32 (transposed)
      int f = t + 256 * i;
      int row = f >> 3, c4 = f & 7;
      float4 v = *(const float4*)&kb[(size_t)(n0 + row) * HD + kt + c4 * 4];
      Ks[c4 * 4 + 0][row] = v.x; Ks[c4 * 4 + 1][row] = v.y;
      Ks[c4 * 4 + 2][row] = v.z; Ks[c4 * 4 + 3][row] = v.w;
    }
    __syncthreads();
#pragma unroll
    for (int kk = 0; kk < 32; kk++) {
      float4 a0 = *(const float4*)&Qs[kk][ty * 8];
      float4 a1 = *(const float4*)&Qs[kk][ty * 8 + 4];
      float4 b4 = *(const float4*)&Ks[kk][tx * 4];
      float a[8] = {a0.x, a0.y, a0.z, a0.w, a1.x, a1.y, a1.z, a1.w};
      float bb[4] = {b4.x, b4.y, b4.z, b4.w};
#pragma unroll
      for (int i = 0; i < 8; i++)
#pragma unroll
        for (int j = 0; j < 4; j++) acc[i][j] += a[i] * bb[j];
    }
    __syncthreads();
  }
#pragma unroll
  for (int i = 0; i < 8; i++) {
    *(float4*)&S[((size_t)bh * L_ + m0 + ty * 8 + i) * L_ + n0 + tx * 4] =
        make_float4(acc[i][0], acc[i][1], acc[i][2], acc[i][3]);
  }
}

// ---------------------------------------------------------------------------
// M[bh,q] = max_s(S[bh,q,idx[q,s]]) - sum_s(...)/L    (unscaled qk)
// ---------------------------------------------------------------------------
__global__ __launch_bounds__(256) void m_k(const float* __restrict__ S,
    const int* __restrict__ idx, float* __restrict__ Mv)
{
  const int qi = blockIdx.x, bh = blockIdx.y, t = threadIdx.x;
  const float* row = S + ((size_t)bh * L_ + qi) * L_;
  const int* ir = idx + (size_t)qi * L_;
  float mx = -1e30f, sm = 0.f;
  for (int s = t; s < L_; s += 256) {
    float v = row[ir[s]];
    mx = fmaxf(mx, v);
    sm += v;
  }
#pragma unroll
  for (int o = 32; o > 0; o >>= 1) {
    mx = fmaxf(mx, __shfl_xor(mx, o));
    sm += __shfl_xor(sm, o);
  }
  __shared__ float wmx[4], wsm[4];
  if ((t & 63) == 0) { wmx[t >> 6] = mx; wsm[t >> 6] = sm; }
  __syncthreads();
  if (t == 0) {
    mx = fmaxf(fmaxf(wmx[0], wmx[1]), fmaxf(wmx[2], wmx[3]));
    sm = wsm[0] + wsm[1] + wsm[2] + wsm[3];
    Mv[(size_t)bh * L_ + qi] = mx - sm * (1.0f / L_);
  }
}

// ---------------------------------------------------------------------------
// Full descending sort of M per (b,h): exactly jax.lax.top_k(M, L) semantics
// (values descending; ties -> lower index first). Bitonic on u64 keys.
// ---------------------------------------------------------------------------
__global__ __launch_bounds__(1024) void sort_k(const float* __restrict__ Mv,
                                               int* __restrict__ top)
{
  __shared__ unsigned long long keys[L_];
  const int bh = blockIdx.x, t = threadIdx.x;
  float m = Mv[(size_t)bh * L_ + t];
  unsigned u = __float_as_uint(m);
  u = (u & 0x80000000u) ? ~u : (u | 0x80000000u);       // order-preserving map
  keys[t] = ((unsigned long long)(~u) << 32) | (unsigned)t;
  __syncthreads();
  for (int k = 2; k <= L_; k <<= 1) {
    for (int j = k >> 1; j > 0; j >>= 1) {
      int ixj = t ^ j;
      if (ixj > t) {
        unsigned long long a = keys[t], b = keys[ixj];
        bool up = ((t & k) == 0);
        if ((a > b) == up) { keys[t] = b; keys[ixj] = a; }
      }
      __syncthreads();
    }
  }
  top[(size_t)bh * L_ + t] = (int)(keys[t] & 0xFFFFFFFFu);
}

// ---------------------------------------------------------------------------
// PV: out[b, u0+r, h*64+d] = softmax(S[bh, top[u0+r], :]*SCALE) @ v[bh]
// 64 u-rows per block, 256 threads, key chunks of 64.
// ---------------------------------------------------------------------------
__global__ __launch_bounds__(256) void pv_k(const float* __restrict__ S,
    const float* __restrict__ v, const int* __restrict__ top,
    float* __restrict__ out)
{
  __shared__ float Ps[64][68];
  __shared__ float Vs[64][68];
  __shared__ int   qrow[64];
  __shared__ float rmax[64], rsum[64];
  const int t = threadIdx.x;
  const int bh = blockIdx.y, u0 = blockIdx.x * 64;
  const int bb_ = bh >> 3, h = bh & 7;

  if (t < 64) qrow[t] = top[(size_t)bh * L_ + u0 + t];
  __syncthreads();

  {                                            // pass 1: row max & sumexp
    const int r = t >> 2, c = t & 3;
    const float4* rf = (const float4*)(S + ((size_t)bh * L_ + qrow[r]) * L_);
    float mx = -1e30f;
    for (int j = 0; j < 64; j++) {
      float4 q4 = rf[c + 4 * j];
      mx = fmaxf(fmaxf(fmaxf(mx, q4.x), q4.y), fmaxf(q4.z, q4.w));
    }
    mx = fmaxf(mx, __shfl_xor(mx, 1));
    mx = fmaxf(mx, __shfl_xor(mx, 2));
    mx *= SCALE;
    float sm = 0.f;
    for (int j = 0; j < 64; j++) {
      float4 q4 = rf[c + 4 * j];
      sm += expf(q4.x * SCALE - mx) + expf(q4.y * SCALE - mx) +
            expf(q4.z * SCALE - mx) + expf(q4.w * SCALE - mx);
    }
    sm += __shfl_xor(sm, 1);
    sm += __shfl_xor(sm, 2);
    if (c == 0) { rmax[r] = mx; rsum[r] = sm; }
  }
  __syncthreads();

  float acc[4][4];
#pragma unroll
  for (int i = 0; i < 4; i++)
#pragma unroll
    for (int j = 0; j < 4; j++) acc[i][j] = 0.f;
  const int rg = t >> 4, dq = t & 15;

  for (int c0 = 0; c0 < L_; c0 += 64) {
#pragma unroll
    for (int i = 0; i < 4; i++) {              // stage V chunk 64x64
      int f = t + 256 * i;
      int kk = f >> 4, d4 = f & 15;
      *(float4*)&Vs[kk][d4 * 4] =
          *(const float4*)&v[((size_t)bh * L_ + c0 + kk) * HD + d4 * 4];
    }
    {                                          // stage P chunk 64x64
      const int r = t >> 2, c = t & 3;
      const float4* rf = (const float4*)(S + ((size_t)bh * L_ + qrow[r]) * L_);
      float mxr = rmax[r];
#pragma unroll
      for (int i = 0; i < 4; i++) {
        int k4 = c * 4 + i;
        float4 q4 = rf[(c0 >> 2) + k4];
        float4 p;
        p.x = expf(q4.x * SCALE - mxr); p.y = expf(q4.y * SCALE - mxr);
        p.z = expf(q4.z * SCALE - mxr); p.w = expf(q4.w * SCALE - mxr);
        *(float4*)&Ps[r][k4 * 4] = p;
      }
    }
    __syncthreads();
#pragma unroll
    for (int k4 = 0; k4 < 16; k4++) {
      float4 p4[4], vv[4];
#pragma unroll
      for (int ri = 0; ri < 4; ri++) p4[ri] = *(const float4*)&Ps[rg * 4 + ri][k4 * 4];
#pragma unroll
      for (int kk = 0; kk < 4; kk++) vv[kk] = *(const float4*)&Vs[k4 * 4 + kk][dq * 4];
#pragma unroll
      for (int ri = 0; ri < 4; ri++) {
        float pk[4] = {p4[ri].x, p4[ri].y, p4[ri].z, p4[ri].w};
#pragma unroll
        for (int kk = 0; kk < 4; kk++) {
          acc[ri][0] += pk[kk] * vv[kk].x;
          acc[ri][1] += pk[kk] * vv[kk].y;
          acc[ri][2] += pk[kk] * vv[kk].z;
          acc[ri][3] += pk[kk] * vv[kk].w;
        }
      }
    }
    __syncthreads();
  }

#pragma unroll
  for (int ri = 0; ri < 4; ri++) {
    int r = rg * 4 + ri;
    float inv = 1.0f / rsum[r];
    float4 o = make_float4(acc[ri][0] * inv, acc[ri][1] * inv,
                           acc[ri][2] * inv, acc[ri][3] * inv);
    *(float4*)&out[((size_t)bb_ * L_ + u0 + r) * DM + h * HD + dq * 4] = o;
  }
}

// ---------------------------------------------------------------------------
// LayerNorm over DM=512: out = LN(xin (+ add)) * g + b. 64 threads per row.
// ---------------------------------------------------------------------------
__global__ __launch_bounds__(64) void ln_k(const float* __restrict__ xin,
    const float* __restrict__ add, const float* __restrict__ g,
    const float* __restrict__ bb, float* __restrict__ out)
{
  const int row = blockIdx.x, t = threadIdx.x;
  const float4* xf = (const float4*)(xin + (size_t)row * DM);
  float4 v0 = xf[t], v1 = xf[t + 64];
  if (add) {
    const float4* af = (const float4*)(add + (size_t)row * DM);
    float4 a0 = af[t], a1 = af[t + 64];
    v0.x += a0.x; v0.y += a0.y; v0.z += a0.z; v0.w += a0.w;
    v1.x += a1.x; v1.y += a1.y; v1.z += a1.z; v1.w += a1.w;
  }
  float s  = v0.x + v0.y + v0.z + v0.w + v1.x + v1.y + v1.z + v1.w;
  float ss = v0.x * v0.x + v0.y * v0.y + v0.z * v0.z + v0.w * v0.w +
             v1.x * v1.x + v1.y * v1.y + v1.z * v1.z + v1.w * v1.w;
#pragma unroll
  for (int o = 32; o > 0; o >>= 1) {
    s  += __shfl_xor(s, o);
    ss += __shfl_xor(ss, o);
  }
  float mean = s * (1.0f / DM);
  float var  = ss * (1.0f / DM) - mean * mean;
  float inv  = 1.0f / sqrtf(var + 1e-5f);
  const float4* gf = (const float4*)g;
  const float4* bf = (const float4*)bb;
  float4 g0 = gf[t], g1 = gf[t + 64], b0 = bf[t], b1 = bf[t + 64];
  float4 o0, o1;
  o0.x = (v0.x - mean) * inv * g0.x + b0.x;
  o0.y = (v0.y - mean) * inv * g0.y + b0.y;
  o0.z = (v0.z - mean) * inv * g0.z + b0.z;
  o0.w = (v0.w - mean) * inv * g0.w + b0.w;
  o1.x = (v1.x - mean) * inv * g1.x + b1.x;
  o1.y = (v1.y - mean) * inv * g1.y + b1.y;
  o1.z = (v1.z - mean) * inv * g1.z + b1.z;
  o1.w = (v1.w - mean) * inv * g1.w + b1.w;
  float4* of = (float4*)(out + (size_t)row * DM);
  of[t] = o0; of[t + 64] = o1;
}

// ---------------------------------------------------------------------------
extern "C" void kernel_launch(void* const* d_in, const int* in_sizes, int n_in,
                              void* d_out, int out_size, void* d_ws, size_t ws_size,
                              hipStream_t stream)
{
  const float* x_enc   = (const float*)d_in[0];
  const int*   sidx    = (const int*)d_in[1];
  const float* W_emb   = (const float*)d_in[2];
  const float* b_emb   = (const float*)d_in[3];
  const float* Wq      = (const float*)d_in[4];
  const float* bq      = (const float*)d_in[5];
  const float* Wk      = (const float*)d_in[6];
  const float* bk      = (const float*)d_in[7];
  const float* Wv      = (const float*)d_in[8];
  const float* bv      = (const float*)d_in[9];
  const float* Wo      = (const float*)d_in[10];
  const float* bo      = (const float*)d_in[11];
  const float* W1      = (const float*)d_in[12];
  const float* b1      = (const float*)d_in[13];
  const float* W2      = (const float*)d_in[14];
  const float* b2      = (const float*)d_in[15];
  const float* g1      = (const float*)d_in[16];
  const float* be1     = (const float*)d_in[17];
  const float* g2      = (const float*)d_in[18];
  const float* be2     = (const float*)d_in[19];
  const float* gN      = (const float*)d_in[20];
  const float* bN      = (const float*)d_in[21];
  const float* W_proj  = (const float*)d_in[22];
  const float* b_proj  = (const float*)d_in[23];

  const int M = B_ * L_;                      // 4096
  char* w = (char*)d_ws;
  float* x    = (float*)w; w += (size_t)M * DM * 4;
  float* qb   = (float*)w; w += (size_t)M * DM * 4;
  float* kb   = (float*)w; w += (size_t)M * DM * 4;
  float* vb   = (float*)w; w += (size_t)M * DM * 4;
  float* attn = (float*)w; w += (size_t)M * DM * 4;
  float* tmp  = (float*)w; w += (size_t)M * DM * 4;
  float* ffn  = (float*)w; w += (size_t)M * DFF * 4;
  float* Mv   = (float*)w; w += (size_t)B_ * H_ * L_ * 4;
  int*   top  = (int*)w;   w += (size_t)B_ * H_ * L_ * 4;
  float* S    = (float*)w; w += (size_t)B_ * H_ * L_ * L_ * 4;

  // embedding + positional encoding
  gemm_k<3><<<dim3(DM / 64, M / 128), 256, 0, stream>>>(x_enc, W_emb, b_emb, x, M, DM, ENCIN);

  for (int il = 0; il < NL; il++) {
    const float* wq = Wq + (size_t)il * DM * DM;
    const float* wk = Wk + (size_t)il * DM * DM;
    const float* wv = Wv + (size_t)il * DM * DM;
    gemm_k<1><<<dim3(8, 32), 256, 0, stream>>>(x, wq, bq + il * DM, qb, M, DM, DM);
    gemm_k<1><<<dim3(8, 32), 256, 0, stream>>>(x, wk, bk + il * DM, kb, M, DM, DM);
    gemm_k<1><<<dim3(8, 32), 256, 0, stream>>>(x, wv, bv + il * DM, vb, M, DM, DM);

    qk_k<<<dim3(16, 8, 32), 256, 0, stream>>>(qb, kb, S);
    m_k<<<dim3(L_, B_ * H_), 256, 0, stream>>>(S, sidx + (size_t)il * L_ * L_, Mv);
    sort_k<<<B_ * H_, 1024, 0, stream>>>(Mv, top);
    pv_k<<<dim3(L_ / 64, B_ * H_), 256, 0, stream>>>(S, vb, top, attn);

    gemm_k<0><<<dim3(8, 32), 256, 0, stream>>>(attn, Wo + (size_t)il * DM * DM, bo + il * DM, tmp, M, DM, DM);
    ln_k<<<M, 64, 0, stream>>>(x, tmp, g1 + il * DM, be1 + il * DM, x);

    gemm_k<2><<<dim3(DFF / 64, M / 128), 256, 0, stream>>>(x, W1 + (size_t)il * DM * DFF, b1 + il * DFF, ffn, M, DFF, DM);
    gemm_k<0><<<dim3(8, 32), 256, 0, stream>>>(ffn, W2 + (size_t)il * DFF * DM, b2 + il * DM, tmp, M, DM, DFF);
    ln_k<<<M, 64, 0, stream>>>(x, tmp, g2 + il * DM, be2 + il * DM, x);
  }

  ln_k<<<M, 64, 0, stream>>>(x, nullptr, gN, bN, x);
  gemm_k<0><<<dim3(COUT / 64, M / 128), 256, 0, stream>>>(x, W_proj, b_proj, (float*)d_out, M, COUT, DM);
}

// Round 2
// 2075.167 us; speedup vs baseline: 1.2369x; 1.2369x over previous
//
#include <hip/hip_runtime.h>
#include <cstdint>
#include <cstddef>

#define B_    4
#define L_    1024
#define ENCIN 64
#define DM    512
#define H_    8
#define HD    64
#define DFF   2048
#define NL    3
#define COUT  64
#define SCALE 0.125f
#define BH    32

typedef __attribute__((ext_vector_type(4))) short short4v;
typedef __attribute__((ext_vector_type(8))) short short8v;
typedef __attribute__((ext_vector_type(4))) float f32x4;
typedef unsigned short u16;

#define MFMA16(a,b,c) __builtin_amdgcn_mfma_f32_16x16x32_bf16(a,b,c,0,0,0)

// global -> LDS async copy, 16B per lane. LDS dest must be the wave-uniform base.
#define GL2LDS(gsrc, ldst) \
  __builtin_amdgcn_global_load_lds( \
      (const __attribute__((address_space(1))) void*)(uintptr_t)(const void*)(gsrc), \
      (__attribute__((address_space(3))) void*)(uintptr_t)(const void*)(ldst), 16, 0, 0)

__device__ __forceinline__ u16 f2bf(float f){
  unsigned u = __float_as_uint(f);
  u += 0x7fffu + ((u >> 16) & 1u);              // RNE
  return (u16)(u >> 16);
}
__device__ __forceinline__ float bf2f(u16 h){
  return __uint_as_float(((unsigned)h) << 16);
}
__device__ __forceinline__ void split2(float v, u16* h, u16* l){
  u16 hh = f2bf(v);
  *h = hh;
  *l = f2bf(v - bf2f(hh));
}

// ---------------------------------------------------------------------------
// Split-bf16 MFMA GEMM: C = A @ B^T + bias where A=[M][K] (hi,lo bf16),
// B given as W^T = [N][K] (hi,lo bf16). acc += Ah*Bh + Ah*Bl + Al*Bh.
// BM=128, BN=64/128, BK=32, 256 threads (4 waves, 2x2), wave tile 64 x BN/2.
// MODE: 0 fp32 C [M][N]; 1 emb (+PE, write x fp32 + xh/xl);
//       2 gelu -> split bf16 [M][N]; 3 q/k -> split bf16 [bh][l][d];
//       4 v -> plain bf16 V^T [bh][d][l].
// ---------------------------------------------------------------------------
template<int BN, int MODE>
__global__ __launch_bounds__(256) void hgemm(
    const u16* __restrict__ Ah, const u16* __restrict__ Al,
    const u16* __restrict__ Bh, const u16* __restrict__ Bl,
    const float* __restrict__ bias,
    float* __restrict__ o32, u16* __restrict__ oh, u16* __restrict__ ol,
    int M, int N, int K)
{
  constexpr int NT = BN / 32;
  __shared__ u16 As0[128*32], As1[128*32];
  __shared__ u16 Bs0[BN*32],  Bs1[BN*32];
  const int t = threadIdx.x, lane = t & 63, wid = t >> 6;
  const int wr = wid >> 1, wc = wid & 1;
  const int fr = lane & 15, fq = lane >> 4;
  const int m0 = blockIdx.y * 128, n0 = blockIdx.x * BN;
  const int arow = lane >> 2, aseg = lane & 3;

  f32x4 acc[4][NT] = {};

  for (int kt = 0; kt < K; kt += 32) {
#pragma unroll
    for (int i = 0; i < 2; i++) {                 // A: 8 calls x 1KB per matrix
      int c = wid + 4*i;
      GL2LDS(&Ah[(size_t)(m0 + c*16 + arow)*K + kt + aseg*8], &As0[c*512]);
      GL2LDS(&Al[(size_t)(m0 + c*16 + arow)*K + kt + aseg*8], &As1[c*512]);
    }
#pragma unroll
    for (int i = 0; i < BN/64; i++) {             // B: BN/16 calls per matrix
      int c = wid + 4*i;
      GL2LDS(&Bh[(size_t)(n0 + c*16 + arow)*K + kt + aseg*8], &Bs0[c*512]);
      GL2LDS(&Bl[(size_t)(n0 + c*16 + arow)*K + kt + aseg*8], &Bs1[c*512]);
    }
    __syncthreads();

    short8v a0[4], a1[4], b0[NT], b1[NT];
#pragma unroll
    for (int m = 0; m < 4; m++) {
      int off = (wr*64 + m*16 + fr)*32 + fq*4;
      short4v x0 = *(const short4v*)&As0[off];
      short4v x1 = *(const short4v*)&As0[off + 16];
      a0[m] = __builtin_shufflevector(x0, x1, 0,1,2,3,4,5,6,7);
      short4v y0 = *(const short4v*)&As1[off];
      short4v y1 = *(const short4v*)&As1[off + 16];
      a1[m] = __builtin_shufflevector(y0, y1, 0,1,2,3,4,5,6,7);
    }
#pragma unroll
    for (int n = 0; n < NT; n++) {
      int off = (wc*(BN/2) + n*16 + fr)*32 + fq*4;
      short4v x0 = *(const short4v*)&Bs0[off];
      short4v x1 = *(const short4v*)&Bs0[off + 16];
      b0[n] = __builtin_shufflevector(x0, x1, 0,1,2,3,4,5,6,7);
      short4v y0 = *(const short4v*)&Bs1[off];
      short4v y1 = *(const short4v*)&Bs1[off + 16];
      b1[n] = __builtin_shufflevector(y0, y1, 0,1,2,3,4,5,6,7);
    }
#pragma unroll
    for (int m = 0; m < 4; m++)
#pragma unroll
      for (int n = 0; n < NT; n++) {
        acc[m][n] = MFMA16(a0[m], b0[n], acc[m][n]);
        acc[m][n] = MFMA16(a0[m], b1[n], acc[m][n]);
        acc[m][n] = MFMA16(a1[m], b0[n], acc[m][n]);
      }
    __syncthreads();
  }

#pragma unroll
  for (int m = 0; m < 4; m++) {
    int gr0 = m0 + wr*64 + m*16 + fq*4;
#pragma unroll
    for (int n = 0; n < NT; n++) {
      int gc = n0 + wc*(BN/2) + n*16 + fr;
      float bv = bias[gc];
#pragma unroll
      for (int r = 0; r < 4; r++) {
        float v = acc[m][n][r] + bv;
        int row = gr0 + r;
        if (MODE == 0) {
          o32[(size_t)row*N + gc] = v;
        } else if (MODE == 1) {
          int li = row & (L_ - 1);
          float dv = expf((float)(gc & ~1) * -0.017988946039015984f);
          float ang = (float)li * dv;
          v += (gc & 1) ? cosf(ang) : sinf(ang);
          size_t ix = (size_t)row*N + gc;
          o32[ix] = v;
          split2(v, &oh[ix], &ol[ix]);
        } else if (MODE == 2) {
          float gv = 0.5f * v * (1.0f + erff(v * 0.70710678118654752f));
          size_t ix = (size_t)row*N + gc;
          split2(gv, &oh[ix], &ol[ix]);
        } else if (MODE == 3) {
          int b = row >> 10, li = row & (L_ - 1);
          int hh2 = gc >> 6, d = gc & 63;
          size_t ix = (((size_t)(b*H_ + hh2))*L_ + li)*HD + d;
          split2(v, &oh[ix], &ol[ix]);
        } else if (MODE == 4) {
          int b = row >> 10, li = row & (L_ - 1);
          int hh2 = gc >> 6, d = gc & 63;
          size_t ix = (((size_t)(b*H_ + hh2))*HD + d)*L_ + li;
          oh[ix] = f2bf(v);
        }
      }
    }
  }
}

// ---------------------------------------------------------------------------
// qk: S[bh][m][n] = q[bh][m][:] . k[bh][n][:] (fp32 out, split-bf16 MFMA)
// 128x128 tile per block, K=64 staged whole, 2 MFMA k-steps.
// ---------------------------------------------------------------------------
__global__ __launch_bounds__(256) void qk_mfma(
    const u16* __restrict__ qh, const u16* __restrict__ ql,
    const u16* __restrict__ kh, const u16* __restrict__ kl,
    float* __restrict__ S)
{
  __shared__ u16 Qs0[128*64], Qs1[128*64], Ks0[128*64], Ks1[128*64];
  const int t = threadIdx.x, lane = t & 63, wid = t >> 6;
  const int wr = wid >> 1, wc = wid & 1;
  const int fr = lane & 15, fq = lane >> 4;
  const int n0 = blockIdx.x * 128, m0 = blockIdx.y * 128, bh = blockIdx.z;
  const int arow = lane >> 3, aseg = lane & 7;
  const u16* qhb = qh + (size_t)bh * L_ * HD;
  const u16* qlb = ql + (size_t)bh * L_ * HD;
  const u16* khb = kh + (size_t)bh * L_ * HD;
  const u16* klb = kl + (size_t)bh * L_ * HD;

#pragma unroll
  for (int i = 0; i < 4; i++) {                   // 16 calls per matrix
    int c = wid + 4*i;
    GL2LDS(&qhb[(size_t)(m0 + c*8 + arow)*HD + aseg*8], &Qs0[c*512]);
    GL2LDS(&qlb[(size_t)(m0 + c*8 + arow)*HD + aseg*8], &Qs1[c*512]);
    GL2LDS(&khb[(size_t)(n0 + c*8 + arow)*HD + aseg*8], &Ks0[c*512]);
    GL2LDS(&klb[(size_t)(n0 + c*8 + arow)*HD + aseg*8], &Ks1[c*512]);
  }
  __syncthreads();

  f32x4 acc[4][4] = {};
#pragma unroll
  for (int ks = 0; ks < 2; ks++) {
    int kg = ks*32 + fq*4;
    short8v a0[4], a1[4], b0[4], b1[4];
#pragma unroll
    for (int m = 0; m < 4; m++) {
      int off = (wr*64 + m*16 + fr)*64 + kg;
      short4v x0 = *(const short4v*)&Qs0[off];
      short4v x1 = *(const short4v*)&Qs0[off + 16];
      a0[m] = __builtin_shufflevector(x0, x1, 0,1,2,3,4,5,6,7);
      short4v y0 = *(const short4v*)&Qs1[off];
      short4v y1 = *(const short4v*)&Qs1[off + 16];
      a1[m] = __builtin_shufflevector(y0, y1, 0,1,2,3,4,5,6,7);
    }
#pragma unroll
    for (int n = 0; n < 4; n++) {
      int off = (wc*64 + n*16 + fr)*64 + kg;
      short4v x0 = *(const short4v*)&Ks0[off];
      short4v x1 = *(const short4v*)&Ks0[off + 16];
      b0[n] = __builtin_shufflevector(x0, x1, 0,1,2,3,4,5,6,7);
      short4v y0 = *(const short4v*)&Ks1[off];
      short4v y1 = *(const short4v*)&Ks1[off + 16];
      b1[n] = __builtin_shufflevector(y0, y1, 0,1,2,3,4,5,6,7);
    }
#pragma unroll
    for (int m = 0; m < 4; m++)
#pragma unroll
      for (int n = 0; n < 4; n++) {
        acc[m][n] = MFMA16(a0[m], b0[n], acc[m][n]);
        acc[m][n] = MFMA16(a0[m], b1[n], acc[m][n]);
        acc[m][n] = MFMA16(a1[m], b0[n], acc[m][n]);
      }
  }

#pragma unroll
  for (int m = 0; m < 4; m++)
#pragma unroll
    for (int n = 0; n < 4; n++)
#pragma unroll
      for (int r = 0; r < 4; r++) {
        int grow = m0 + wr*64 + m*16 + fq*4 + r;
        int gcol = n0 + wc*64 + n*16 + fr;
        S[((size_t)bh*L_ + grow)*L_ + gcol] = acc[m][n][r];
      }
}

// ---------------------------------------------------------------------------
// M[bh,q] = max_s(S[bh,q,idx[q,s]]) - sum_s(...)/L
// ---------------------------------------------------------------------------
__global__ __launch_bounds__(256) void m_k(const float* __restrict__ S,
    const int* __restrict__ idx, float* __restrict__ Mv)
{
  const int qi = blockIdx.x, bh = blockIdx.y, t = threadIdx.x;
  const float* row = S + ((size_t)bh * L_ + qi) * L_;
  const int* ir = idx + (size_t)qi * L_;
  float mx = -1e30f, sm = 0.f;
  for (int s = t; s < L_; s += 256) {
    float v = row[ir[s]];
    mx = fmaxf(mx, v);
    sm += v;
  }
#pragma unroll
  for (int o = 32; o > 0; o >>= 1) {
    mx = fmaxf(mx, __shfl_xor(mx, o));
    sm += __shfl_xor(sm, o);
  }
  __shared__ float wmx[4], wsm[4];
  if ((t & 63) == 0) { wmx[t >> 6] = mx; wsm[t >> 6] = sm; }
  __syncthreads();
  if (t == 0) {
    mx = fmaxf(fmaxf(wmx[0], wmx[1]), fmaxf(wmx[2], wmx[3]));
    sm = wsm[0] + wsm[1] + wsm[2] + wsm[3];
    Mv[(size_t)bh * L_ + qi] = mx - sm * (1.0f / L_);
  }
}

// ---------------------------------------------------------------------------
// Row softmax stats over S*SCALE: rmax (already scaled), rsum = sum exp
// ---------------------------------------------------------------------------
__global__ __launch_bounds__(256) void sm_k(const float* __restrict__ S,
    float* __restrict__ rmax, float* __restrict__ rsum)
{
  const int row = blockIdx.x, bh = blockIdx.y, t = threadIdx.x;
  const float4* rf = (const float4*)&S[((size_t)bh*L_ + row)*L_];
  float4 v = rf[t];
  float mx = fmaxf(fmaxf(v.x, v.y), fmaxf(v.z, v.w));
  __shared__ float red[4], red2[4];
#pragma unroll
  for (int o = 32; o > 0; o >>= 1) mx = fmaxf(mx, __shfl_xor(mx, o));
  if ((t & 63) == 0) red[t >> 6] = mx;
  __syncthreads();
  mx = fmaxf(fmaxf(red[0], red[1]), fmaxf(red[2], red[3])) * SCALE;
  float sm = expf(v.x*SCALE - mx) + expf(v.y*SCALE - mx) +
             expf(v.z*SCALE - mx) + expf(v.w*SCALE - mx);
#pragma unroll
  for (int o = 32; o > 0; o >>= 1) sm += __shfl_xor(sm, o);
  if ((t & 63) == 0) red2[t >> 6] = sm;
  __syncthreads();
  if (t == 0) {
    rmax[(size_t)bh*L_ + row] = mx;
    rsum[(size_t)bh*L_ + row] = red2[0] + red2[1] + red2[2] + red2[3];
  }
}

// ---------------------------------------------------------------------------
// Full descending sort of M per (b,h) -> rank (inverse permutation):
// rank[orig_row] = sorted position. jax.lax.top_k tie semantics preserved.
// ---------------------------------------------------------------------------
__global__ __launch_bounds__(1024) void sort_k(const float* __restrict__ Mv,
                                               int* __restrict__ rank)
{
  __shared__ unsigned long long keys[L_];
  const int bh = blockIdx.x, t = threadIdx.x;
  float m = Mv[(size_t)bh * L_ + t];
  unsigned u = __float_as_uint(m);
  u = (u & 0x80000000u) ? ~u : (u | 0x80000000u);
  keys[t] = ((unsigned long long)(~u) << 32) | (unsigned)t;
  __syncthreads();
  for (int k = 2; k <= L_; k <<= 1) {
    for (int j = k >> 1; j > 0; j >>= 1) {
      int ixj = t ^ j;
      if (ixj > t) {
        unsigned long long a = keys[t], b = keys[ixj];
        bool up = ((t & k) == 0);
        if ((a > b) == up) { keys[t] = b; keys[ixj] = a; }
      }
      __syncthreads();
    }
  }
  int orig = (int)(keys[t] & 0xFFFFFFFFu);
  rank[(size_t)bh * L_ + orig] = t;
}

// ---------------------------------------------------------------------------
// PV (MFMA): for standard rows l0..l0+127 compute softmax(S*SCALE) @ V,
// write to permuted position u = rank[l] as split-bf16 attn [b][u][h*64+d].
// P staged in LDS as bf16 [128][64] per chunk; V^T staged [64][64].
// ---------------------------------------------------------------------------
__global__ __launch_bounds__(256) void pv_mfma(
    const float* __restrict__ S, const u16* __restrict__ vt,
    const float* __restrict__ rmx, const float* __restrict__ rsm,
    const int* __restrict__ rank,
    u16* __restrict__ ath, u16* __restrict__ atl)
{
  __shared__ u16 Ps[128*64];
  __shared__ u16 Vs[64*64];
  __shared__ float rmaxS[128], rsumS[128];
  __shared__ int rankS[128];
  const int t = threadIdx.x, lane = t & 63, wid = t >> 6;
  const int wr = wid >> 1, wc = wid & 1;
  const int fr = lane & 15, fq = lane >> 4;
  const int l0 = blockIdx.x * 128, bh = blockIdx.y;
  const int bb = bh >> 3, hh = bh & 7;
  const int arow = lane >> 3, aseg = lane & 7;

  if (t < 128) {
    rmaxS[t] = rmx[(size_t)bh*L_ + l0 + t];
    rsumS[t] = rsm[(size_t)bh*L_ + l0 + t];
    rankS[t] = rank[(size_t)bh*L_ + l0 + t];
  }
  __syncthreads();

  f32x4 acc[4][2] = {};
  for (int c0 = 0; c0 < L_; c0 += 64) {
#pragma unroll
    for (int i = 0; i < 2; i++) {                 // V^T chunk: 8 calls
      int c = wid + 4*i;
      GL2LDS(&vt[((size_t)bh*HD + c*8 + arow)*L_ + c0 + aseg*8], &Vs[c*512]);
    }
#pragma unroll
    for (int i = 0; i < 8; i++) {                 // P chunk: compute + LDS
      int f = t + 256*i;
      int row = f >> 4, q = f & 15;
      float4 s4 = *(const float4*)&S[((size_t)bh*L_ + l0 + row)*L_ + c0 + q*4];
      float mxr = rmaxS[row];
      short4v p4 = { (short)f2bf(expf(s4.x*SCALE - mxr)),
                     (short)f2bf(expf(s4.y*SCALE - mxr)),
                     (short)f2bf(expf(s4.z*SCALE - mxr)),
                     (short)f2bf(expf(s4.w*SCALE - mxr)) };
      *(short4v*)&Ps[row*64 + q*4] = p4;
    }
    __syncthreads();
#pragma unroll
    for (int ks = 0; ks < 2; ks++) {
      int kg = ks*32 + fq*4;
      short8v a[4], b[2];
#pragma unroll
      for (int m = 0; m < 4; m++) {
        int off = (wr*64 + m*16 + fr)*64 + kg;
        short4v x0 = *(const short4v*)&Ps[off];
        short4v x1 = *(const short4v*)&Ps[off + 16];
        a[m] = __builtin_shufflevector(x0, x1, 0,1,2,3,4,5,6,7);
      }
#pragma unroll
      for (int n = 0; n < 2; n++) {
        int off = (wc*32 + n*16 + fr)*64 + kg;
        short4v x0 = *(const short4v*)&Vs[off];
        short4v x1 = *(const short4v*)&Vs[off + 16];
        b[n] = __builtin_shufflevector(x0, x1, 0,1,2,3,4,5,6,7);
      }
#pragma unroll
      for (int m = 0; m < 4; m++)
#pragma unroll
        for (int n = 0; n < 2; n++)
          acc[m][n] = MFMA16(a[m], b[n], acc[m][n]);
    }
    __syncthreads();
  }

#pragma unroll
  for (int m = 0; m < 4; m++)
#pragma unroll
    for (int n = 0; n < 2; n++)
#pragma unroll
      for (int r = 0; r < 4; r++) {
        int lrow = wr*64 + m*16 + fq*4 + r;
        int u = rankS[lrow];
        int d = wc*32 + n*16 + fr;
        float o = acc[m][n][r] / rsumS[lrow];
        size_t ix = ((size_t)bb*L_ + u)*DM + hh*HD + d;
        split2(o, &ath[ix], &atl[ix]);
      }
}

// ---------------------------------------------------------------------------
// LayerNorm over DM=512 + emit fp32 x and split-bf16 xh/xl
// ---------------------------------------------------------------------------
__global__ __launch_bounds__(64) void ln_k(const float* __restrict__ xin,
    const float* __restrict__ add, const float* __restrict__ g,
    const float* __restrict__ bb, float* __restrict__ out,
    u16* __restrict__ oh, u16* __restrict__ ol)
{
  const int row = blockIdx.x, t = threadIdx.x;
  const float4* xf = (const float4*)(xin + (size_t)row * DM);
  float4 v0 = xf[t], v1 = xf[t + 64];
  if (add) {
    const float4* af = (const float4*)(add + (size_t)row * DM);
    float4 a0 = af[t], a1 = af[t + 64];
    v0.x += a0.x; v0.y += a0.y; v0.z += a0.z; v0.w += a0.w;
    v1.x += a1.x; v1.y += a1.y; v1.z += a1.z; v1.w += a1.w;
  }
  float s  = v0.x + v0.y + v0.z + v0.w + v1.x + v1.y + v1.z + v1.w;
  float ss = v0.x*v0.x + v0.y*v0.y + v0.z*v0.z + v0.w*v0.w +
             v1.x*v1.x + v1.y*v1.y + v1.z*v1.z + v1.w*v1.w;
#pragma unroll
  for (int o = 32; o > 0; o >>= 1) { s += __shfl_xor(s, o); ss += __shfl_xor(ss, o); }
  float mean = s * (1.0f / DM);
  float var  = ss * (1.0f / DM) - mean * mean;
  float inv  = 1.0f / sqrtf(var + 1e-5f);
  const float4* gf = (const float4*)g;
  const float4* bf = (const float4*)bb;
  float4 g0 = gf[t], g1 = gf[t + 64], b0 = bf[t], b1 = bf[t + 64];
  float o0[4], o1[4];
  o0[0] = (v0.x-mean)*inv*g0.x + b0.x; o0[1] = (v0.y-mean)*inv*g0.y + b0.y;
  o0[2] = (v0.z-mean)*inv*g0.z + b0.z; o0[3] = (v0.w-mean)*inv*g0.w + b0.w;
  o1[0] = (v1.x-mean)*inv*g1.x + b1.x; o1[1] = (v1.y-mean)*inv*g1.y + b1.y;
  o1[2] = (v1.z-mean)*inv*g1.z + b1.z; o1[3] = (v1.w-mean)*inv*g1.w + b1.w;
  float4* of = (float4*)(out + (size_t)row * DM);
  of[t]      = make_float4(o0[0], o0[1], o0[2], o0[3]);
  of[t + 64] = make_float4(o1[0], o1[1], o1[2], o1[3]);
  size_t base = (size_t)row * DM;
#pragma unroll
  for (int j = 0; j < 4; j++) {
    split2(o0[j], &oh[base + t*4 + j],       &ol[base + t*4 + j]);
    split2(o1[j], &oh[base + 256 + t*4 + j], &ol[base + 256 + t*4 + j]);
  }
}

// ---------------------------------------------------------------------------
// Weight transpose + split: W [K][N] fp32 -> Th, Tl [N][K] bf16
// ---------------------------------------------------------------------------
__global__ __launch_bounds__(256) void wt_k(const float* __restrict__ W,
    u16* __restrict__ Th, u16* __restrict__ Tl, int K, int N)
{
  __shared__ float tile[32][33];
  const int k0 = blockIdx.y * 32, n0 = blockIdx.x * 32;
  const int c = threadIdx.x & 31, r4 = threadIdx.x >> 5;
#pragma unroll
  for (int i = 0; i < 4; i++) {
    int r = r4 * 4 + i;
    tile[r][c] = W[(size_t)(k0 + r) * N + n0 + c];
  }
  __syncthreads();
#pragma unroll
  for (int i = 0; i < 4; i++) {
    int r = r4 * 4 + i;
    float v = tile[c][r];
    split2(v, &Th[(size_t)(n0 + r) * K + k0 + c], &Tl[(size_t)(n0 + r) * K + k0 + c]);
  }
}

// ---------------------------------------------------------------------------
// Elementwise fp32 -> split bf16 (x_enc)
// ---------------------------------------------------------------------------
__global__ __launch_bounds__(256) void split_k(const float* __restrict__ in,
    u16* __restrict__ oh, u16* __restrict__ ol, int n4)
{
  int i = blockIdx.x * 256 + threadIdx.x;
  if (i < n4) {
    float4 v = ((const float4*)in)[i];
    split2(v.x, &oh[i*4+0], &ol[i*4+0]);
    split2(v.y, &oh[i*4+1], &ol[i*4+1]);
    split2(v.z, &oh[i*4+2], &ol[i*4+2]);
    split2(v.w, &oh[i*4+3], &ol[i*4+3]);
  }
}

// ---------------------------------------------------------------------------
extern "C" void kernel_launch(void* const* d_in, const int* in_sizes, int n_in,
                              void* d_out, int out_size, void* d_ws, size_t ws_size,
                              hipStream_t stream)
{
  const float* x_enc   = (const float*)d_in[0];
  const int*   sidx    = (const int*)d_in[1];
  const float* W_emb   = (const float*)d_in[2];
  const float* b_emb   = (const float*)d_in[3];
  const float* Wq      = (const float*)d_in[4];
  const float* bq      = (const float*)d_in[5];
  const float* Wk      = (const float*)d_in[6];
  const float* bk      = (const float*)d_in[7];
  const float* Wv      = (const float*)d_in[8];
  const float* bv      = (const float*)d_in[9];
  const float* Wo      = (const float*)d_in[10];
  const float* bo      = (const float*)d_in[11];
  const float* W1      = (const float*)d_in[12];
  const float* b1      = (const float*)d_in[13];
  const float* W2      = (const float*)d_in[14];
  const float* b2      = (const float*)d_in[15];
  const float* g1      = (const float*)d_in[16];
  const float* be1     = (const float*)d_in[17];
  const float* g2      = (const float*)d_in[18];
  const float* be2     = (const float*)d_in[19];
  const float* gN      = (const float*)d_in[20];
  const float* bN      = (const float*)d_in[21];
  const float* W_proj  = (const float*)d_in[22];
  const float* b_proj  = (const float*)d_in[23];

  const int M = B_ * L_;                          // 4096
  char* w = (char*)d_ws;
  float* S   = (float*)w;  w += (size_t)BH * L_ * L_ * 4;     // 128 MB
  float* x   = (float*)w;  w += (size_t)M * DM * 4;
  u16* xh    = (u16*)w;    w += (size_t)M * DM * 2;
  u16* xl    = (u16*)w;    w += (size_t)M * DM * 2;
  u16* qh_   = (u16*)w;    w += (size_t)BH * L_ * HD * 2;
  u16* ql_   = (u16*)w;    w += (size_t)BH * L_ * HD * 2;
  u16* kh_   = (u16*)w;    w += (size_t)BH * L_ * HD * 2;
  u16* kl_   = (u16*)w;    w += (size_t)BH * L_ * HD * 2;
  u16* vt_   = (u16*)w;    w += (size_t)BH * L_ * HD * 2;
  u16* ath   = (u16*)w;    w += (size_t)M * DM * 2;
  u16* atl   = (u16*)w;    w += (size_t)M * DM * 2;
  float* rmx_ = (float*)w; w += (size_t)BH * L_ * 4;
  float* rsm_ = (float*)w; w += (size_t)BH * L_ * 4;
  float* Mv_  = (float*)w; w += (size_t)BH * L_ * 4;
  int* rank_  = (int*)w;   w += (size_t)BH * L_ * 4;
  // per-layer (reused) weight buffers
  u16* WqTh = (u16*)w; w += (size_t)DM*DM*2;
  u16* WqTl = (u16*)w; w += (size_t)DM*DM*2;
  u16* WkTh = (u16*)w; w += (size_t)DM*DM*2;
  u16* WkTl = (u16*)w; w += (size_t)DM*DM*2;
  u16* WvTh = (u16*)w; w += (size_t)DM*DM*2;
  u16* WvTl = (u16*)w; w += (size_t)DM*DM*2;
  u16* WoTh = (u16*)w; w += (size_t)DM*DM*2;
  u16* WoTl = (u16*)w; w += (size_t)DM*DM*2;
  u16* W1Th = (u16*)w; w += (size_t)DFF*DM*2;
  u16* W1Tl = (u16*)w; w += (size_t)DFF*DM*2;
  u16* W2Th = (u16*)w; w += (size_t)DM*DFF*2;
  u16* W2Tl = (u16*)w; w += (size_t)DM*DFF*2;
  u16* WeTh = (u16*)w; w += (size_t)DM*ENCIN*2;
  u16* WeTl = (u16*)w; w += (size_t)DM*ENCIN*2;
  u16* WpTh = (u16*)w; w += (size_t)COUT*DM*2;
  u16* WpTl = (u16*)w; w += (size_t)COUT*DM*2;
  // temporal aliases inside S (S live only qk..pv within a layer):
  u16* yh  = (u16*)S;                                        // 16 MB (FFN act hi)
  u16* yl  = (u16*)((char*)S + (size_t)M*DFF*2);             // 16 MB
  float* tmp = (float*)((char*)S + 2*(size_t)M*DFF*2);       // 8 MB @ 32M
  u16* xeh = (u16*)((char*)S + 64u*1024u*1024u);             // pre-loop only
  u16* xel = xeh + (size_t)M*ENCIN;

  // --- pre-loop: conversions + embedding ---
  split_k<<<dim3((M*ENCIN/4 + 255)/256), 256, 0, stream>>>(x_enc, xeh, xel, M*ENCIN/4);
  wt_k<<<dim3(DM/32, ENCIN/32), 256, 0, stream>>>(W_emb, WeTh, WeTl, ENCIN, DM);
  wt_k<<<dim3(COUT/32, DM/32), 256, 0, stream>>>(W_proj, WpTh, WpTl, DM, COUT);
  hgemm<64,1><<<dim3(DM/64, M/128), 256, 0, stream>>>(
      xeh, xel, WeTh, WeTl, b_emb, x, xh, xl, M, DM, ENCIN);

  for (int il = 0; il < NL; il++) {
    wt_k<<<dim3(DM/32, DM/32), 256, 0, stream>>>(Wq + (size_t)il*DM*DM, WqTh, WqTl, DM, DM);
    wt_k<<<dim3(DM/32, DM/32), 256, 0, stream>>>(Wk + (size_t)il*DM*DM, WkTh, WkTl, DM, DM);
    wt_k<<<dim3(DM/32, DM/32), 256, 0, stream>>>(Wv + (size_t)il*DM*DM, WvTh, WvTl, DM, DM);
    wt_k<<<dim3(DM/32, DM/32), 256, 0, stream>>>(Wo + (size_t)il*DM*DM, WoTh, WoTl, DM, DM);
    wt_k<<<dim3(DFF/32, DM/32), 256, 0, stream>>>(W1 + (size_t)il*DM*DFF, W1Th, W1Tl, DM, DFF);
    wt_k<<<dim3(DM/32, DFF/32), 256, 0, stream>>>(W2 + (size_t)il*DFF*DM, W2Th, W2Tl, DFF, DM);

    hgemm<64,3><<<dim3(DM/64, M/128), 256, 0, stream>>>(
        xh, xl, WqTh, WqTl, bq + il*DM, nullptr, qh_, ql_, M, DM, DM);
    hgemm<64,3><<<dim3(DM/64, M/128), 256, 0, stream>>>(
        xh, xl, WkTh, WkTl, bk + il*DM, nullptr, kh_, kl_, M, DM, DM);
    hgemm<64,4><<<dim3(DM/64, M/128), 256, 0, stream>>>(
        xh, xl, WvTh, WvTl, bv + il*DM, nullptr, vt_, nullptr, M, DM, DM);

    qk_mfma<<<dim3(L_/128, L_/128, BH), 256, 0, stream>>>(qh_, ql_, kh_, kl_, S);
    m_k<<<dim3(L_, BH), 256, 0, stream>>>(S, sidx + (size_t)il*L_*L_, Mv_);
    sm_k<<<dim3(L_, BH), 256, 0, stream>>>(S, rmx_, rsm_);
    sort_k<<<BH, 1024, 0, stream>>>(Mv_, rank_);
    pv_mfma<<<dim3(L_/128, BH), 256, 0, stream>>>(S, vt_, rmx_, rsm_, rank_, ath, atl);

    hgemm<64,0><<<dim3(DM/64, M/128), 256, 0, stream>>>(
        ath, atl, WoTh, WoTl, bo + il*DM, tmp, nullptr, nullptr, M, DM, DM);
    ln_k<<<M, 64, 0, stream>>>(x, tmp, g1 + il*DM, be1 + il*DM, x, xh, xl);

    hgemm<128,2><<<dim3(DFF/128, M/128), 256, 0, stream>>>(
        xh, xl, W1Th, W1Tl, b1 + il*DFF, nullptr, yh, yl, M, DFF, DM);
    hgemm<64,0><<<dim3(DM/64, M/128), 256, 0, stream>>>(
        yh, yl, W2Th, W2Tl, b2 + il*DM, tmp, nullptr, nullptr, M, DM, DFF);
    ln_k<<<M, 64, 0, stream>>>(x, tmp, g2 + il*DM, be2 + il*DM, x, xh, xl);
  }

  ln_k<<<M, 64, 0, stream>>>(x, nullptr, gN, bN, x, xh, xl);
  hgemm<64,0><<<dim3(COUT/64, M/128), 256, 0, stream>>>(
      xh, xl, WpTh, WpTl, b_proj, (float*)d_out, nullptr, nullptr, M, COUT, DM);
}

// Round 3
// 1803.320 us; speedup vs baseline: 1.4233x; 1.1507x over previous
//
#include <hip/hip_runtime.h>
#include <cstdint>
#include <cstddef>

#define B_    4
#define L_    1024
#define ENCIN 64
#define DM    512
#define H_    8
#define HD    64
#define DFF   2048
#define NL    3
#define COUT  64
#define SCALE 0.125f
#define BH    32

typedef __attribute__((ext_vector_type(4))) short short4v;
typedef __attribute__((ext_vector_type(8))) short short8v;
typedef __attribute__((ext_vector_type(4))) float f32x4;
typedef unsigned short u16;

#define MFMA16(a,b,c) __builtin_amdgcn_mfma_f32_16x16x32_bf16(a,b,c,0,0,0)

#define GL2LDS(gsrc, ldst) \
  __builtin_amdgcn_global_load_lds( \
      (const __attribute__((address_space(1))) void*)(uintptr_t)(const void*)(gsrc), \
      (__attribute__((address_space(3))) void*)(uintptr_t)(const void*)(ldst), 16, 0, 0)

__device__ __forceinline__ u16 f2bf(float f){
  unsigned u = __float_as_uint(f);
  u += 0x7fffu + ((u >> 16) & 1u);              // RNE
  return (u16)(u >> 16);
}
__device__ __forceinline__ float bf2f(u16 h){
  return __uint_as_float(((unsigned)h) << 16);
}
__device__ __forceinline__ void split2(float v, u16* h, u16* l){
  u16 hh = f2bf(v);
  *h = hh;
  *l = f2bf(v - bf2f(hh));
}

// ---------------------------------------------------------------------------
// Split-bf16 MFMA GEMM, min-2-phase double-buffered. BM=128, BN=64, BK=32,
// 4 waves (2x2), wave tile 64x32 (4x2 frags). A=[M][K] hi/lo, B=W^T=[N][K].
// acc += Ah*Bh + Ah*Bl + Al*Bh  (3 MFMA per frag pair).
// MODE: 0 fp32 out + bias; 1 emb (+PE, x fp32 + xh/xl); 2 gelu->split;
//       3 fused QKV epilogue (q,k split [bh][l][d]; v bf16 V^T [bh][d][l]);
//       5 split-K fp32 partial (no bias), z = blockIdx.z.
// ---------------------------------------------------------------------------
template<int MODE>
__global__ __launch_bounds__(256) void hgemm(
    const u16* __restrict__ Ah, const u16* __restrict__ Al,
    const u16* __restrict__ Bh, const u16* __restrict__ Bl,
    const float* __restrict__ bias1, const float* __restrict__ bias2,
    const float* __restrict__ bias3,
    float* __restrict__ o32, u16* __restrict__ oh, u16* __restrict__ ol,
    u16* __restrict__ oh2, u16* __restrict__ ol2, u16* __restrict__ ov,
    int Mtot, int N, int K, int klen)
{
  __shared__ u16 As[2][2][128*32];
  __shared__ u16 Bs[2][2][64*32];
  const int t = threadIdx.x, lane = t & 63, wid = t >> 6;
  const int wr = wid >> 1, wc = wid & 1;
  const int fr = lane & 15, fq = lane >> 4;
  const int m0 = blockIdx.y * 128, n0 = blockIdx.x * 64;
  const int z = blockIdx.z;
  const int kbase = z * klen;
  const int srow = lane >> 2, sseg = lane & 3;      // 16 rows / 1KB call

  const int nk = klen / 32;

  auto stage = [&](int buf, int kt) {
#pragma unroll
    for (int i = 0; i < 2; i++) {
      int c = wid + 4*i;
      GL2LDS(&Ah[(size_t)(m0 + c*16 + srow)*K + kt + sseg*8], &As[buf][0][c*512]);
      GL2LDS(&Al[(size_t)(m0 + c*16 + srow)*K + kt + sseg*8], &As[buf][1][c*512]);
    }
    {
      int c = wid;
      GL2LDS(&Bh[(size_t)(n0 + c*16 + srow)*K + kt + sseg*8], &Bs[buf][0][c*512]);
      GL2LDS(&Bl[(size_t)(n0 + c*16 + srow)*K + kt + sseg*8], &Bs[buf][1][c*512]);
    }
  };

  f32x4 acc[4][2] = {};
  stage(0, kbase);
  __syncthreads();

  for (int it = 0; it < nk; ++it) {
    int cur = it & 1;
    if (it + 1 < nk) stage(cur ^ 1, kbase + (it+1)*32);

    short8v a0[4], a1[4], b0[2], b1[2];
#pragma unroll
    for (int m = 0; m < 4; m++) {
      int off = (wr*64 + m*16 + fr)*32 + fq*4;
      short4v x0 = *(const short4v*)&As[cur][0][off];
      short4v x1 = *(const short4v*)&As[cur][0][off + 16];
      a0[m] = __builtin_shufflevector(x0, x1, 0,1,2,3,4,5,6,7);
      short4v y0 = *(const short4v*)&As[cur][1][off];
      short4v y1 = *(const short4v*)&As[cur][1][off + 16];
      a1[m] = __builtin_shufflevector(y0, y1, 0,1,2,3,4,5,6,7);
    }
#pragma unroll
    for (int n = 0; n < 2; n++) {
      int off = (wc*32 + n*16 + fr)*32 + fq*4;
      short4v x0 = *(const short4v*)&Bs[cur][0][off];
      short4v x1 = *(const short4v*)&Bs[cur][0][off + 16];
      b0[n] = __builtin_shufflevector(x0, x1, 0,1,2,3,4,5,6,7);
      short4v y0 = *(const short4v*)&Bs[cur][1][off];
      short4v y1 = *(const short4v*)&Bs[cur][1][off + 16];
      b1[n] = __builtin_shufflevector(y0, y1, 0,1,2,3,4,5,6,7);
    }
#pragma unroll
    for (int m = 0; m < 4; m++)
#pragma unroll
      for (int n = 0; n < 2; n++) {
        acc[m][n] = MFMA16(a0[m], b0[n], acc[m][n]);
        acc[m][n] = MFMA16(a0[m], b1[n], acc[m][n]);
        acc[m][n] = MFMA16(a1[m], b0[n], acc[m][n]);
      }
    __syncthreads();
  }

#pragma unroll
  for (int m = 0; m < 4; m++) {
#pragma unroll
    for (int n = 0; n < 2; n++) {
      int gc = n0 + wc*32 + n*16 + fr;
#pragma unroll
      for (int r = 0; r < 4; r++) {
        int row = m0 + wr*64 + m*16 + fq*4 + r;
        float v = acc[m][n][r];
        if (MODE == 5) {
          o32[((size_t)z*Mtot + row)*N + gc] = v;
        } else if (MODE == 0) {
          o32[(size_t)row*N + gc] = v + bias1[gc];
        } else if (MODE == 1) {
          v += bias1[gc];
          int li = row & (L_ - 1);
          float dv = expf((float)(gc & ~1) * -0.017988946039015984f);
          float ang = (float)li * dv;
          v += (gc & 1) ? cosf(ang) : sinf(ang);
          size_t ix = (size_t)row*N + gc;
          o32[ix] = v;
          split2(v, &oh[ix], &ol[ix]);
        } else if (MODE == 2) {
          v += bias1[gc];
          float gv = 0.5f * v * (1.0f + erff(v * 0.70710678118654752f));
          size_t ix = (size_t)row*N + gc;
          split2(gv, &oh[ix], &ol[ix]);
        } else if (MODE == 3) {
          int b = row >> 10, li = row & (L_ - 1);
          int sub = gc >> 9, h = (gc >> 6) & 7, d = gc & 63;
          if (sub == 0) {
            v += bias1[gc];
            size_t ix = (((size_t)(b*H_ + h))*L_ + li)*HD + d;
            split2(v, &oh[ix], &ol[ix]);
          } else if (sub == 1) {
            v += bias2[gc - 512];
            size_t ix = (((size_t)(b*H_ + h))*L_ + li)*HD + d;
            split2(v, &oh2[ix], &ol2[ix]);
          } else {
            v += bias3[gc - 1024];
            size_t ix = (((size_t)(b*H_ + h))*HD + d)*L_ + li;
            ov[ix] = f2bf(v);
          }
        }
      }
    }
  }
}

// ---------------------------------------------------------------------------
// qk: S[bh][m][n] = q[bh][m][:].k[bh][n][:] (fp32, split-bf16 MFMA) with
// FUSED per-tile softmax partial stats (per wave's 64-col half):
// pmax/psum [bh*L][16] -> combined by smc_k.
// ---------------------------------------------------------------------------
__global__ __launch_bounds__(256) void qk_mfma(
    const u16* __restrict__ qh, const u16* __restrict__ ql,
    const u16* __restrict__ kh, const u16* __restrict__ kl,
    float* __restrict__ S, float* __restrict__ pmax, float* __restrict__ psum)
{
  __shared__ u16 Qs0[128*64], Qs1[128*64], Ks0[128*64], Ks1[128*64];
  const int t = threadIdx.x, lane = t & 63, wid = t >> 6;
  const int wr = wid >> 1, wc = wid & 1;
  const int fr = lane & 15, fq = lane >> 4;
  const int n0 = blockIdx.x * 128, m0 = blockIdx.y * 128, bh = blockIdx.z;
  const int srow = lane >> 3, sseg = lane & 7;
  const u16* qhb = qh + (size_t)bh * L_ * HD;
  const u16* qlb = ql + (size_t)bh * L_ * HD;
  const u16* khb = kh + (size_t)bh * L_ * HD;
  const u16* klb = kl + (size_t)bh * L_ * HD;

#pragma unroll
  for (int i = 0; i < 4; i++) {
    int c = wid + 4*i;
    GL2LDS(&qhb[(size_t)(m0 + c*8 + srow)*HD + sseg*8], &Qs0[c*512]);
    GL2LDS(&qlb[(size_t)(m0 + c*8 + srow)*HD + sseg*8], &Qs1[c*512]);
    GL2LDS(&khb[(size_t)(n0 + c*8 + srow)*HD + sseg*8], &Ks0[c*512]);
    GL2LDS(&klb[(size_t)(n0 + c*8 + srow)*HD + sseg*8], &Ks1[c*512]);
  }
  __syncthreads();

  f32x4 acc[4][4] = {};
#pragma unroll
  for (int ks = 0; ks < 2; ks++) {
    int kg = ks*32 + fq*4;
    short8v a0[4], a1[4], b0[4], b1[4];
#pragma unroll
    for (int m = 0; m < 4; m++) {
      int off = (wr*64 + m*16 + fr)*64 + kg;
      short4v x0 = *(const short4v*)&Qs0[off];
      short4v x1 = *(const short4v*)&Qs0[off + 16];
      a0[m] = __builtin_shufflevector(x0, x1, 0,1,2,3,4,5,6,7);
      short4v y0 = *(const short4v*)&Qs1[off];
      short4v y1 = *(const short4v*)&Qs1[off + 16];
      a1[m] = __builtin_shufflevector(y0, y1, 0,1,2,3,4,5,6,7);
    }
#pragma unroll
    for (int n = 0; n < 4; n++) {
      int off = (wc*64 + n*16 + fr)*64 + kg;
      short4v x0 = *(const short4v*)&Ks0[off];
      short4v x1 = *(const short4v*)&Ks0[off + 16];
      b0[n] = __builtin_shufflevector(x0, x1, 0,1,2,3,4,5,6,7);
      short4v y0 = *(const short4v*)&Ks1[off];
      short4v y1 = *(const short4v*)&Ks1[off + 16];
      b1[n] = __builtin_shufflevector(y0, y1, 0,1,2,3,4,5,6,7);
    }
#pragma unroll
    for (int m = 0; m < 4; m++)
#pragma unroll
      for (int n = 0; n < 4; n++) {
        acc[m][n] = MFMA16(a0[m], b0[n], acc[m][n]);
        acc[m][n] = MFMA16(a0[m], b1[n], acc[m][n]);
        acc[m][n] = MFMA16(a1[m], b0[n], acc[m][n]);
      }
  }

  // write S
#pragma unroll
  for (int m = 0; m < 4; m++)
#pragma unroll
    for (int n = 0; n < 4; n++)
#pragma unroll
      for (int r = 0; r < 4; r++) {
        int grow = m0 + wr*64 + m*16 + fq*4 + r;
        int gcol = n0 + wc*64 + n*16 + fr;
        S[((size_t)bh*L_ + grow)*L_ + gcol] = acc[m][n][r];
      }

  // fused partial softmax stats over this wave's 64 cols
  const int tix = blockIdx.x*2 + wc;
#pragma unroll
  for (int m = 0; m < 4; m++) {
    float mx[4], sm[4];
#pragma unroll
    for (int r = 0; r < 4; r++) {
      float v = fmaxf(fmaxf(acc[m][0][r], acc[m][1][r]),
                      fmaxf(acc[m][2][r], acc[m][3][r]));
#pragma unroll
      for (int o2 = 1; o2 < 16; o2 <<= 1) v = fmaxf(v, __shfl_xor(v, o2));
      mx[r] = v * SCALE;
      float s = 0.f;
#pragma unroll
      for (int n = 0; n < 4; n++) s += expf(acc[m][n][r]*SCALE - mx[r]);
#pragma unroll
      for (int o2 = 1; o2 < 16; o2 <<= 1) s += __shfl_xor(s, o2);
      sm[r] = s;
    }
    if (fr == 0) {
#pragma unroll
      for (int r = 0; r < 4; r++) {
        int grow = m0 + wr*64 + m*16 + fq*4 + r;
        size_t ix = ((size_t)bh*L_ + grow)*16 + tix;
        pmax[ix] = mx[r];
        psum[ix] = sm[r];
      }
    }
  }
}

// combine 16 partials per row -> rmx, rsm
__global__ __launch_bounds__(256) void smc_k(const float* __restrict__ pmax,
    const float* __restrict__ psum, float* __restrict__ rmx, float* __restrict__ rsm)
{
  const int g = threadIdx.x & 15;
  const size_t flat = (size_t)blockIdx.x*16 + (threadIdx.x >> 4);
  float m = pmax[flat*16 + g], s = psum[flat*16 + g];
  float gm = m;
#pragma unroll
  for (int o = 1; o < 16; o <<= 1) gm = fmaxf(gm, __shfl_xor(gm, o));
  float gs = s * expf(m - gm);
#pragma unroll
  for (int o = 1; o < 16; o <<= 1) gs += __shfl_xor(gs, o);
  if (g == 0) { rmx[flat] = gm; rsm[flat] = gs; }
}

// ---------------------------------------------------------------------------
// M[bh,q] = max_s(S[bh,q,idx[q,s]]) - sum_s(...)/L
// ---------------------------------------------------------------------------
__global__ __launch_bounds__(256) void m_k(const float* __restrict__ S,
    const int* __restrict__ idx, float* __restrict__ Mv)
{
  const int qi = blockIdx.x, bh = blockIdx.y, t = threadIdx.x;
  const float* row = S + ((size_t)bh * L_ + qi) * L_;
  const int* ir = idx + (size_t)qi * L_;
  float mx = -1e30f, sm = 0.f;
  for (int s = t; s < L_; s += 256) {
    float v = row[ir[s]];
    mx = fmaxf(mx, v);
    sm += v;
  }
#pragma unroll
  for (int o = 32; o > 0; o >>= 1) {
    mx = fmaxf(mx, __shfl_xor(mx, o));
    sm += __shfl_xor(sm, o);
  }
  __shared__ float wmx[4], wsm[4];
  if ((t & 63) == 0) { wmx[t >> 6] = mx; wsm[t >> 6] = sm; }
  __syncthreads();
  if (t == 0) {
    mx = fmaxf(fmaxf(wmx[0], wmx[1]), fmaxf(wmx[2], wmx[3]));
    sm = wsm[0] + wsm[1] + wsm[2] + wsm[3];
    Mv[(size_t)bh * L_ + qi] = mx - sm * (1.0f / L_);
  }
}

// ---------------------------------------------------------------------------
// Full descending sort of M per (b,h) -> rank[orig] = sorted position
// ---------------------------------------------------------------------------
__global__ __launch_bounds__(1024) void sort_k(const float* __restrict__ Mv,
                                               int* __restrict__ rank)
{
  __shared__ unsigned long long keys[L_];
  const int bh = blockIdx.x, t = threadIdx.x;
  float m = Mv[(size_t)bh * L_ + t];
  unsigned u = __float_as_uint(m);
  u = (u & 0x80000000u) ? ~u : (u | 0x80000000u);
  keys[t] = ((unsigned long long)(~u) << 32) | (unsigned)t;
  __syncthreads();
  for (int k = 2; k <= L_; k <<= 1) {
    for (int j = k >> 1; j > 0; j >>= 1) {
      int ixj = t ^ j;
      if (ixj > t) {
        unsigned long long a = keys[t], b = keys[ixj];
        bool up = ((t & k) == 0);
        if ((a > b) == up) { keys[t] = b; keys[ixj] = a; }
      }
      __syncthreads();
    }
  }
  int orig = (int)(keys[t] & 0xFFFFFFFFu);
  rank[(size_t)bh * L_ + orig] = t;
}

// ---------------------------------------------------------------------------
// PV (MFMA): 64 rows/block. softmax(S*SCALE) @ V -> permuted split-bf16 attn
// ---------------------------------------------------------------------------
__global__ __launch_bounds__(256) void pv_mfma(
    const float* __restrict__ S, const u16* __restrict__ vt,
    const float* __restrict__ rmx, const float* __restrict__ rsm,
    const int* __restrict__ rank,
    u16* __restrict__ ath, u16* __restrict__ atl)
{
  __shared__ u16 Ps[64*64];
  __shared__ u16 Vs[64*64];
  __shared__ float rmaxS[64], rsumS[64];
  __shared__ int rankS[64];
  const int t = threadIdx.x, lane = t & 63, wid = t >> 6;
  const int wr = wid >> 1, wc = wid & 1;
  const int fr = lane & 15, fq = lane >> 4;
  const int l0 = blockIdx.x * 64, bh = blockIdx.y;
  const int bb = bh >> 3, hh = bh & 7;
  const int srow = lane >> 3, sseg = lane & 7;

  if (t < 64) {
    rmaxS[t] = rmx[(size_t)bh*L_ + l0 + t];
    rsumS[t] = rsm[(size_t)bh*L_ + l0 + t];
    rankS[t] = rank[(size_t)bh*L_ + l0 + t];
  }
  __syncthreads();

  f32x4 acc[2][2] = {};
  for (int c0 = 0; c0 < L_; c0 += 64) {
#pragma unroll
    for (int i = 0; i < 2; i++) {
      int c = wid + 4*i;
      GL2LDS(&vt[((size_t)bh*HD + c*8 + srow)*L_ + c0 + sseg*8], &Vs[c*512]);
    }
#pragma unroll
    for (int i = 0; i < 4; i++) {
      int f = t + 256*i;
      int row = f >> 4, q = f & 15;
      float4 s4 = *(const float4*)&S[((size_t)bh*L_ + l0 + row)*L_ + c0 + q*4];
      float mxr = rmaxS[row];
      short4v p4 = { (short)f2bf(expf(s4.x*SCALE - mxr)),
                     (short)f2bf(expf(s4.y*SCALE - mxr)),
                     (short)f2bf(expf(s4.z*SCALE - mxr)),
                     (short)f2bf(expf(s4.w*SCALE - mxr)) };
      *(short4v*)&Ps[row*64 + q*4] = p4;
    }
    __syncthreads();
#pragma unroll
    for (int ks = 0; ks < 2; ks++) {
      int kg = ks*32 + fq*4;
      short8v a[2], b[2];
#pragma unroll
      for (int m = 0; m < 2; m++) {
        int off = (wr*32 + m*16 + fr)*64 + kg;
        short4v x0 = *(const short4v*)&Ps[off];
        short4v x1 = *(const short4v*)&Ps[off + 16];
        a[m] = __builtin_shufflevector(x0, x1, 0,1,2,3,4,5,6,7);
      }
#pragma unroll
      for (int n = 0; n < 2; n++) {
        int off = (wc*32 + n*16 + fr)*64 + kg;
        short4v x0 = *(const short4v*)&Vs[off];
        short4v x1 = *(const short4v*)&Vs[off + 16];
        b[n] = __builtin_shufflevector(x0, x1, 0,1,2,3,4,5,6,7);
      }
#pragma unroll
      for (int m = 0; m < 2; m++)
#pragma unroll
        for (int n = 0; n < 2; n++)
          acc[m][n] = MFMA16(a[m], b[n], acc[m][n]);
    }
    __syncthreads();
  }

#pragma unroll
  for (int m = 0; m < 2; m++)
#pragma unroll
    for (int n = 0; n < 2; n++)
#pragma unroll
      for (int r = 0; r < 4; r++) {
        int lrow = wr*32 + m*16 + fq*4 + r;
        int u = rankS[lrow];
        int d = wc*32 + n*16 + fr;
        float o = acc[m][n][r] / rsumS[lrow];
        size_t ix = ((size_t)bb*L_ + u)*DM + hh*HD + d;
        split2(o, &ath[ix], &atl[ix]);
      }
}

// ---------------------------------------------------------------------------
// LayerNorm + optional split-K partial reduce + bias:
// v = x + sum_p part[p] + bias; out = LN(v)*g+b (fp32 + split bf16)
// ---------------------------------------------------------------------------
__global__ __launch_bounds__(64) void ln2_k(const float* __restrict__ xin,
    const float* __restrict__ part, int np, const float* __restrict__ bias,
    const float* __restrict__ g, const float* __restrict__ bb,
    float* __restrict__ out, u16* __restrict__ oh, u16* __restrict__ ol)
{
  const int row = blockIdx.x, t = threadIdx.x;
  const float4* xf = (const float4*)(xin + (size_t)row * DM);
  float4 v0 = xf[t], v1 = xf[t + 64];
  for (int p = 0; p < np; p++) {
    const float4* af = (const float4*)(part + ((size_t)p*(B_*L_) + row) * DM);
    float4 a0 = af[t], a1 = af[t + 64];
    v0.x += a0.x; v0.y += a0.y; v0.z += a0.z; v0.w += a0.w;
    v1.x += a1.x; v1.y += a1.y; v1.z += a1.z; v1.w += a1.w;
  }
  if (bias) {
    const float4* cf = (const float4*)bias;
    float4 c0 = cf[t], c1 = cf[t + 64];
    v0.x += c0.x; v0.y += c0.y; v0.z += c0.z; v0.w += c0.w;
    v1.x += c1.x; v1.y += c1.y; v1.z += c1.z; v1.w += c1.w;
  }
  float s  = v0.x + v0.y + v0.z + v0.w + v1.x + v1.y + v1.z + v1.w;
  float ss = v0.x*v0.x + v0.y*v0.y + v0.z*v0.z + v0.w*v0.w +
             v1.x*v1.x + v1.y*v1.y + v1.z*v1.z + v1.w*v1.w;
#pragma unroll
  for (int o = 32; o > 0; o >>= 1) { s += __shfl_xor(s, o); ss += __shfl_xor(ss, o); }
  float mean = s * (1.0f / DM);
  float var  = ss * (1.0f / DM) - mean * mean;
  float inv  = 1.0f / sqrtf(var + 1e-5f);
  const float4* gf = (const float4*)g;
  const float4* bf = (const float4*)bb;
  float4 g0 = gf[t], g1 = gf[t + 64], b0 = bf[t], b1 = bf[t + 64];
  float o0[4], o1[4];
  o0[0] = (v0.x-mean)*inv*g0.x + b0.x; o0[1] = (v0.y-mean)*inv*g0.y + b0.y;
  o0[2] = (v0.z-mean)*inv*g0.z + b0.z; o0[3] = (v0.w-mean)*inv*g0.w + b0.w;
  o1[0] = (v1.x-mean)*inv*g1.x + b1.x; o1[1] = (v1.y-mean)*inv*g1.y + b1.y;
  o1[2] = (v1.z-mean)*inv*g1.z + b1.z; o1[3] = (v1.w-mean)*inv*g1.w + b1.w;
  float4* of = (float4*)(out + (size_t)row * DM);
  of[t]      = make_float4(o0[0], o0[1], o0[2], o0[3]);
  of[t + 64] = make_float4(o1[0], o1[1], o1[2], o1[3]);
  size_t base = (size_t)row * DM;
#pragma unroll
  for (int j = 0; j < 4; j++) {
    split2(o0[j], &oh[base + t*4 + j],       &ol[base + t*4 + j]);
    split2(o1[j], &oh[base + 256 + t*4 + j], &ol[base + 256 + t*4 + j]);
  }
}

// ---------------------------------------------------------------------------
// Weight transpose + split: W [K][N] fp32 -> Th, Tl [N][K] bf16 (batched z)
// ---------------------------------------------------------------------------
__global__ __launch_bounds__(256) void wt_k(const float* __restrict__ W,
    u16* __restrict__ Th, u16* __restrict__ Tl, int K, int N,
    size_t wz, size_t tz)
{
  W  += (size_t)blockIdx.z * wz;
  Th += (size_t)blockIdx.z * tz;
  Tl += (size_t)blockIdx.z * tz;
  __shared__ float tile[32][33];
  const int k0 = blockIdx.y * 32, n0 = blockIdx.x * 32;
  const int c = threadIdx.x & 31, r4 = threadIdx.x >> 5;
#pragma unroll
  for (int i = 0; i < 4; i++) {
    int r = r4 * 4 + i;
    tile[r][c] = W[(size_t)(k0 + r) * N + n0 + c];
  }
  __syncthreads();
#pragma unroll
  for (int i = 0; i < 4; i++) {
    int r = r4 * 4 + i;
    float v = tile[c][r];
    split2(v, &Th[(size_t)(n0 + r) * K + k0 + c], &Tl[(size_t)(n0 + r) * K + k0 + c]);
  }
}

__global__ __launch_bounds__(256) void split_k(const float* __restrict__ in,
    u16* __restrict__ oh, u16* __restrict__ ol, int n4)
{
  int i = blockIdx.x * 256 + threadIdx.x;
  if (i < n4) {
    float4 v = ((const float4*)in)[i];
    split2(v.x, &oh[i*4+0], &ol[i*4+0]);
    split2(v.y, &oh[i*4+1], &ol[i*4+1]);
    split2(v.z, &oh[i*4+2], &ol[i*4+2]);
    split2(v.w, &oh[i*4+3], &ol[i*4+3]);
  }
}

// ---------------------------------------------------------------------------
extern "C" void kernel_launch(void* const* d_in, const int* in_sizes, int n_in,
                              void* d_out, int out_size, void* d_ws, size_t ws_size,
                              hipStream_t stream)
{
  const float* x_enc   = (const float*)d_in[0];
  const int*   sidx    = (const int*)d_in[1];
  const float* W_emb   = (const float*)d_in[2];
  const float* b_emb   = (const float*)d_in[3];
  const float* Wq      = (const float*)d_in[4];
  const float* bq      = (const float*)d_in[5];
  const float* Wk      = (const float*)d_in[6];
  const float* bk      = (const float*)d_in[7];
  const float* Wv      = (const float*)d_in[8];
  const float* bv      = (const float*)d_in[9];
  const float* Wo      = (const float*)d_in[10];
  const float* bo      = (const float*)d_in[11];
  const float* W1      = (const float*)d_in[12];
  const float* b1      = (const float*)d_in[13];
  const float* W2      = (const float*)d_in[14];
  const float* b2      = (const float*)d_in[15];
  const float* g1      = (const float*)d_in[16];
  const float* be1     = (const float*)d_in[17];
  const float* g2      = (const float*)d_in[18];
  const float* be2     = (const float*)d_in[19];
  const float* gN      = (const float*)d_in[20];
  const float* bN      = (const float*)d_in[21];
  const float* W_proj  = (const float*)d_in[22];
  const float* b_proj  = (const float*)d_in[23];

  const int M = B_ * L_;                          // 4096
  char* w = (char*)d_ws;
  float* S   = (float*)w;  w += (size_t)BH * L_ * L_ * 4;     // 128 MB
  float* x   = (float*)w;  w += (size_t)M * DM * 4;
  u16* xh    = (u16*)w;    w += (size_t)M * DM * 2;
  u16* xl    = (u16*)w;    w += (size_t)M * DM * 2;
  u16* qh_   = (u16*)w;    w += (size_t)BH * L_ * HD * 2;
  u16* ql_   = (u16*)w;    w += (size_t)BH * L_ * HD * 2;
  u16* kh_   = (u16*)w;    w += (size_t)BH * L_ * HD * 2;
  u16* kl_   = (u16*)w;    w += (size_t)BH * L_ * HD * 2;
  u16* vt_   = (u16*)w;    w += (size_t)BH * L_ * HD * 2;
  u16* ath   = (u16*)w;    w += (size_t)M * DM * 2;
  u16* atl   = (u16*)w;    w += (size_t)M * DM * 2;
  float* rmx_ = (float*)w; w += (size_t)BH * L_ * 4;
  float* rsm_ = (float*)w; w += (size_t)BH * L_ * 4;
  float* Mv_  = (float*)w; w += (size_t)BH * L_ * 4;
  int* rank_  = (int*)w;   w += (size_t)BH * L_ * 4;
  float* pmax_ = (float*)w; w += (size_t)BH * L_ * 16 * 4;    // 2 MB
  float* psum_ = (float*)w; w += (size_t)BH * L_ * 16 * 4;    // 2 MB
  // persistent transposed/split weights (computed once)
  u16* WqkvTh = (u16*)w; w += (size_t)NL*1536*DM*2;
  u16* WqkvTl = (u16*)w; w += (size_t)NL*1536*DM*2;
  u16* WoTh   = (u16*)w; w += (size_t)NL*DM*DM*2;
  u16* WoTl   = (u16*)w; w += (size_t)NL*DM*DM*2;
  u16* W1Th   = (u16*)w; w += (size_t)NL*DFF*DM*2;
  u16* W1Tl   = (u16*)w; w += (size_t)NL*DFF*DM*2;
  u16* W2Th   = (u16*)w; w += (size_t)NL*DM*DFF*2;
  u16* W2Tl   = (u16*)w; w += (size_t)NL*DM*DFF*2;
  u16* WeTh   = (u16*)w; w += (size_t)DM*ENCIN*2;
  u16* WeTl   = (u16*)w; w += (size_t)DM*ENCIN*2;
  u16* WpTh   = (u16*)w; w += (size_t)COUT*DM*2;
  u16* WpTl   = (u16*)w; w += (size_t)COUT*DM*2;
  // aliases inside S (dead outside qk..pv window):
  u16*   yh     = (u16*)S;                                     // 16 MB
  u16*   yl     = (u16*)((char*)S + 16u*1024u*1024u);          // 16 MB
  float* partWo = (float*)((char*)S + 32u*1024u*1024u);        // 16 MB (2 parts)
  float* partW2 = (float*)((char*)S + 48u*1024u*1024u);        // 32 MB (4 parts)
  u16*   xeh    = (u16*)((char*)S + 80u*1024u*1024u);
  u16*   xel    = xeh + (size_t)M*ENCIN;

  // --- one-time: input split + all weight transposes ---
  split_k<<<dim3((M*ENCIN/4 + 255)/256), 256, 0, stream>>>(x_enc, xeh, xel, M*ENCIN/4);
  wt_k<<<dim3(DM/32, DM/32, NL), 256, 0, stream>>>(Wq, WqkvTh,            WqkvTl,            DM, DM, (size_t)DM*DM, (size_t)1536*DM);
  wt_k<<<dim3(DM/32, DM/32, NL), 256, 0, stream>>>(Wk, WqkvTh + 512*DM,   WqkvTl + 512*DM,   DM, DM, (size_t)DM*DM, (size_t)1536*DM);
  wt_k<<<dim3(DM/32, DM/32, NL), 256, 0, stream>>>(Wv, WqkvTh + 1024*DM,  WqkvTl + 1024*DM,  DM, DM, (size_t)DM*DM, (size_t)1536*DM);
  wt_k<<<dim3(DM/32, DM/32, NL), 256, 0, stream>>>(Wo, WoTh, WoTl, DM, DM, (size_t)DM*DM, (size_t)DM*DM);
  wt_k<<<dim3(DFF/32, DM/32, NL), 256, 0, stream>>>(W1, W1Th, W1Tl, DM, DFF, (size_t)DM*DFF, (size_t)DFF*DM);
  wt_k<<<dim3(DM/32, DFF/32, NL), 256, 0, stream>>>(W2, W2Th, W2Tl, DFF, DM, (size_t)DFF*DM, (size_t)DM*DFF);
  wt_k<<<dim3(DM/32, ENCIN/32, 1), 256, 0, stream>>>(W_emb, WeTh, WeTl, ENCIN, DM, 0, 0);
  wt_k<<<dim3(COUT/32, DM/32, 1), 256, 0, stream>>>(W_proj, WpTh, WpTl, DM, COUT, 0, 0);

  // embedding + PE
  hgemm<1><<<dim3(DM/64, M/128, 1), 256, 0, stream>>>(
      xeh, xel, WeTh, WeTl, b_emb, nullptr, nullptr,
      x, xh, xl, nullptr, nullptr, nullptr, M, DM, ENCIN, ENCIN);

  for (int il = 0; il < NL; il++) {
    // fused QKV: N = 1536
    hgemm<3><<<dim3(1536/64, M/128, 1), 256, 0, stream>>>(
        xh, xl, WqkvTh + (size_t)il*1536*DM, WqkvTl + (size_t)il*1536*DM,
        bq + il*DM, bk + il*DM, bv + il*DM,
        nullptr, qh_, ql_, kh_, kl_, vt_, M, 1536, DM, DM);

    qk_mfma<<<dim3(L_/128, L_/128, BH), 256, 0, stream>>>(qh_, ql_, kh_, kl_, S, pmax_, psum_);
    smc_k<<<dim3(BH*L_/16), 256, 0, stream>>>(pmax_, psum_, rmx_, rsm_);
    m_k<<<dim3(L_, BH), 256, 0, stream>>>(S, sidx + (size_t)il*L_*L_, Mv_);
    sort_k<<<BH, 1024, 0, stream>>>(Mv_, rank_);
    pv_mfma<<<dim3(L_/64, BH), 256, 0, stream>>>(S, vt_, rmx_, rsm_, rank_, ath, atl);

    // Wo: split-K x2 -> partials, reduced in ln2
    hgemm<5><<<dim3(DM/64, M/128, 2), 256, 0, stream>>>(
        ath, atl, WoTh + (size_t)il*DM*DM, WoTl + (size_t)il*DM*DM,
        nullptr, nullptr, nullptr,
        partWo, nullptr, nullptr, nullptr, nullptr, nullptr, M, DM, DM, DM/2);
    ln2_k<<<M, 64, 0, stream>>>(x, partWo, 2, bo + il*DM, g1 + il*DM, be1 + il*DM, x, xh, xl);

    // FFN
    hgemm<2><<<dim3(DFF/64, M/128, 1), 256, 0, stream>>>(
        xh, xl, W1Th + (size_t)il*DFF*DM, W1Tl + (size_t)il*DFF*DM,
        b1 + il*DFF, nullptr, nullptr,
        nullptr, yh, yl, nullptr, nullptr, nullptr, M, DFF, DM, DM);
    hgemm<5><<<dim3(DM/64, M/128, 4), 256, 0, stream>>>(
        yh, yl, W2Th + (size_t)il*DM*DFF, W2Tl + (size_t)il*DM*DFF,
        nullptr, nullptr, nullptr,
        partW2, nullptr, nullptr, nullptr, nullptr, nullptr, M, DM, DFF, DFF/4);
    ln2_k<<<M, 64, 0, stream>>>(x, partW2, 4, b2 + il*DM, g2 + il*DM, be2 + il*DM, x, xh, xl);
  }

  ln2_k<<<M, 64, 0, stream>>>(x, nullptr, 0, nullptr, gN, bN, x, xh, xl);
  hgemm<0><<<dim3(COUT/64, M/128, 1), 256, 0, stream>>>(
      xh, xl, WpTh, WpTl, b_proj, nullptr, nullptr,
      (float*)d_out, nullptr, nullptr, nullptr, nullptr, nullptr, M, COUT, DM, DM);
}